// Round 9
// baseline (86.059 us; speedup 1.0000x reference)
//
#include <hip/hip_runtime.h>

// KeySegPred — round 9: balanced fusion of conv + mlp in ONE kernel.
//   K1 fused_kernel (1024x512):
//     blocks 0..255   : r3-style MFMA MLP (inline fp32->bf16 weight convert) -> out_ws
//     blocks 256..1023: dense_w -> wtab bf16 (plain grid-stride, 393K threads x ~16 iters)
//     (independent outputs; no intra-kernel dependency. 1024 blocks x 8 waves
//      = 8192 waves = full chip residency -> memory phase hides under MFMA phase)
//   K2 logits_kernel (4096x256): 16-deep bf16 row gather + LDS transpose-reduce.
//   Fallback (ws too small): mlp-only + fp32 logits gather.

#define BATCH 4096
#define DSEG 128
#define DS_ 258
#define DM7 512
#define DM8 256
#define NCAND 64
#define DWC 252
#define TSLOTS 96
#define SEGN 100000
#define MLP_BLOCKS 256
#define CONV_BLOCKS 768

typedef short bf16x8 __attribute__((ext_vector_type(8)));
typedef short bf16x4 __attribute__((ext_vector_type(4)));
typedef float f32x4 __attribute__((ext_vector_type(4)));

static __device__ __forceinline__ short f2bf(float f) {
    union { float f; unsigned u; } v; v.f = f;
    unsigned r = (v.u + 0x7FFFu + ((v.u >> 16) & 1u)) >> 16;  // RNE
    return (short)r;
}
static __device__ __forceinline__ bf16x4 cvt4(float4 v) {
    bf16x4 s;
    s[0] = f2bf(v.x); s[1] = f2bf(v.y); s[2] = f2bf(v.z); s[3] = f2bf(v.w);
    return s;
}
static __device__ __forceinline__ float bfu2f(unsigned u16) {
    union { unsigned u; float f; } v; v.u = u16 << 16; return v.f;
}

template <bool CONV>
__global__ __launch_bounds__(512) void fused_kernel(
    const int* __restrict__ src, const int* __restrict__ dest,
    const float* __restrict__ offset,
    const float* __restrict__ emb_feat, const float* __restrict__ emb_dest,
    const float* __restrict__ w1, const float* __restrict__ b1,
    const float* __restrict__ bn_gamma, const float* __restrict__ bn_beta,
    const float* __restrict__ bn_mean, const float* __restrict__ bn_var,
    const float* __restrict__ w2, const float* __restrict__ b2,
    const float* __restrict__ dense_w, short* __restrict__ wtab,
    float* __restrict__ out_ws)
{
    __shared__ __align__(16) short hlds[16][520];
    const int tid = threadIdx.x;

    if (CONV && blockIdx.x >= MLP_BLOCKS) {
        // ---- conv role: plain grid-stride stream-convert ----
        const size_t T = (size_t)CONV_BLOCKS * 512;            // 393,216
        const size_t n4 = (size_t)SEGN * DWC / 4;              // 6,300,000
        const float4* __restrict__ s4 = (const float4*)dense_w;
        bf16x4* __restrict__ d4 = (bf16x4*)wtab;
        for (size_t i = (size_t)(blockIdx.x - MLP_BLOCKS) * 512 + tid; i < n4; i += T) {
            d4[i] = cvt4(s4[i]);
        }
        return;
    }

    // ---- MLP role (r3 math: inline fp32->bf16 weight conversion) ----
    const int w    = tid >> 6;     // wave 0..7
    const int lane = tid & 63;
    const int lg   = lane >> 4;    // 0..3
    const int lr   = lane & 15;    // 0..15
    const int b0   = blockIdx.x * 16;

    const int si = src[b0 + lr];
    const int di = dest[b0 + lr];
    const float* fb = emb_feat + (size_t)si * DSEG;
    const float* db = emb_dest + (size_t)di * DSEG;
    bf16x8 a1[8];
#pragma unroll
    for (int s = 0; s < 8; ++s) {
        const float* p = (s < 4) ? (fb + s * 32 + lg * 8)
                                 : (db + (s - 4) * 32 + lg * 8);
        const float4 x = *(const float4*)p;
        const float4 y = *(const float4*)(p + 4);
        bf16x8 t;
        t[0] = f2bf(x.x); t[1] = f2bf(x.y); t[2] = f2bf(x.z); t[3] = f2bf(x.w);
        t[4] = f2bf(y.x); t[5] = f2bf(y.y); t[6] = f2bf(y.z); t[7] = f2bf(y.w);
        a1[s] = t;
    }
    float off1[4], off2[4];
#pragma unroll
    for (int q = 0; q < 4; ++q) {
        const float4 o = *(const float4*)(offset + (size_t)(b0 + lg * 4 + q) * 4);
        off1[q] = o.y; off2[q] = o.z;
    }

#pragma unroll
    for (int nt = 0; nt < 4; ++nt) {
        const int n = (w * 4 + nt) * 16 + lr;
        const float* wrow = w1 + (size_t)n * DS_;
        f32x4 acc = {0.f, 0.f, 0.f, 0.f};
#pragma unroll
        for (int s = 0; s < 8; ++s) {
            const float* p = wrow + s * 32 + lg * 8;
            const float2 x0 = *(const float2*)(p);
            const float2 x1 = *(const float2*)(p + 2);
            const float2 x2 = *(const float2*)(p + 4);
            const float2 x3 = *(const float2*)(p + 6);
            bf16x8 bb;
            bb[0] = f2bf(x0.x); bb[1] = f2bf(x0.y); bb[2] = f2bf(x1.x); bb[3] = f2bf(x1.y);
            bb[4] = f2bf(x2.x); bb[5] = f2bf(x2.y); bb[6] = f2bf(x3.x); bb[7] = f2bf(x3.y);
            acc = __builtin_amdgcn_mfma_f32_16x16x32_bf16(a1[s], bb, acc, 0, 0, 0);
        }
        const float2 wtail = *(const float2*)(wrow + 256);
        const float scale = bn_gamma[n] / sqrtf(bn_var[n] + 1e-6f);
        const float shift = bn_beta[n] - bn_mean[n] * scale;
        const float bias  = b1[n];
#pragma unroll
        for (int q = 0; q < 4; ++q) {
            float v = acc[q] + bias + off1[q] * wtail.x + off2[q] * wtail.y;
            v = fmaf(v, scale, shift);
            v = fmaxf(v, 0.f);
            hlds[lg * 4 + q][n] = f2bf(v);
        }
    }
    __syncthreads();

    bf16x8 a2[16];
#pragma unroll
    for (int s = 0; s < 16; ++s) {
        a2[s] = *(const bf16x8*)&hlds[lr][s * 32 + lg * 8];
    }
#pragma unroll
    for (int nt = 0; nt < 2; ++nt) {
        const int n = (w * 2 + nt) * 16 + lr;
        const float* wrow = w2 + (size_t)n * DM7;
        f32x4 acc = {0.f, 0.f, 0.f, 0.f};
#pragma unroll
        for (int s = 0; s < 16; ++s) {
            const float4 x = *(const float4*)(wrow + s * 32 + lg * 8);
            const float4 y = *(const float4*)(wrow + s * 32 + lg * 8 + 4);
            bf16x8 bb;
            bb[0] = f2bf(x.x); bb[1] = f2bf(x.y); bb[2] = f2bf(x.z); bb[3] = f2bf(x.w);
            bb[4] = f2bf(y.x); bb[5] = f2bf(y.y); bb[6] = f2bf(y.z); bb[7] = f2bf(y.w);
            acc = __builtin_amdgcn_mfma_f32_16x16x32_bf16(a2[s], bb, acc, 0, 0, 0);
        }
        const float bias = b2[n];
#pragma unroll
        for (int q = 0; q < 4; ++q) {
            out_ws[(size_t)(b0 + lg * 4 + q) * DM8 + n] = acc[q] + bias;
        }
    }
}

template <bool BF16TAB>
__global__ __launch_bounds__(256) void logits_kernel_t(
    const int* __restrict__ dest, const int* __restrict__ tt,
    const int* __restrict__ candidates,
    const float* __restrict__ dense_w, const unsigned short* __restrict__ wtab,
    const float* __restrict__ dense_b,
    const float* __restrict__ cand_w, const float* __restrict__ cand_b,
    const float* __restrict__ segs_src, const float* __restrict__ segs_trg,
    const float* __restrict__ traffic_pop,
    const float* __restrict__ out_ws,
    float* __restrict__ logits)
{
    __shared__ float plds[4][16][67];
    const int b = blockIdx.x;
    const int tid = threadIdx.x;
    const int wave = tid >> 6;
    const int lane = tid & 63;
    const int mbase = wave * 16;

    int candv = 0;
    if (lane < 16) candv = candidates[b * NCAND + mbase + lane];

    const int ll = (lane < 63) ? lane : 62;
    float4 dwf[16];
    uint2  dwb[16];
    if (BF16TAB) {
#pragma unroll
        for (int i = 0; i < 16; ++i) {
            const int ci = __shfl(candv, i, 64);
            dwb[i] = *(const uint2*)(wtab + (size_t)ci * DWC + ll * 4);  // 8B/lane
        }
    } else {
#pragma unroll
        for (int i = 0; i < 16; ++i) {
            const int ci = __shfl(candv, i, 64);
            dwf[i] = *(const float4*)(dense_w + (size_t)ci * DWC + ll * 4);
        }
    }

    float4 o4 = *(const float4*)(out_ws + (size_t)b * DM8 + ll * 4);
    if (lane == 63) { o4.x = 0.f; o4.y = 0.f; o4.z = 0.f; o4.w = 0.f; }

    float tail = 0.f;
    if (lane < 16) {
        const float4 t4 = *(const float4*)(out_ws + (size_t)b * DM8 + DWC);
        const int db = dest[b];
        const float2 dsx = *(const float2*)(segs_src + 2 * (size_t)db);
        const float2 sx = *(const float2*)(segs_src + 2 * (size_t)candv);
        const float2 tx = *(const float2*)(segs_trg + 2 * (size_t)candv);
        const float v1x = dsx.x - sx.x, v1y = dsx.y - sx.y;
        const float v2x = tx.x - sx.x, v2y = tx.y - sx.y;
        const float num = v1x * v2x + v1y * v2y;
        const float den = fmaxf(sqrtf(v1x * v1x + v1y * v1y) *
                                sqrtf(v2x * v2x + v2y * v2y), 1e-8f);
        const float cosv = num / den;
        const float tf = traffic_pop[(size_t)candv * TSLOTS + tt[b]];
        const float e0 = fmaf(cosv, cand_w[0], fmaf(tf, cand_w[1], cand_b[0]));
        const float e1 = fmaf(cosv, cand_w[2], fmaf(tf, cand_w[3], cand_b[1]));
        const float e2 = fmaf(cosv, cand_w[4], fmaf(tf, cand_w[5], cand_b[2]));
        const float e3 = fmaf(cosv, cand_w[6], fmaf(tf, cand_w[7], cand_b[3]));
        tail = e0 * t4.x + e1 * t4.y + e2 * t4.z + e3 * t4.w + dense_b[candv];
    }

#pragma unroll
    for (int i = 0; i < 16; ++i) {
        float p;
        if (BF16TAB) {
            p =      bfu2f(dwb[i].x & 0xFFFFu) * o4.x;
            p = fmaf(bfu2f(dwb[i].x >> 16),      o4.y, p);
            p = fmaf(bfu2f(dwb[i].y & 0xFFFFu),  o4.z, p);
            p = fmaf(bfu2f(dwb[i].y >> 16),      o4.w, p);
        } else {
            p = dwf[i].x * o4.x + dwf[i].y * o4.y + dwf[i].z * o4.z + dwf[i].w * o4.w;
        }
        plds[wave][i][lane] = p;
    }
    __syncthreads();

    const int cc = lane >> 2;
    const int qq = lane & 3;
    float s = 0.f;
#pragma unroll
    for (int j = 0; j < 16; ++j) s += plds[wave][cc][qq * 16 + j];
    s += __shfl_xor(s, 1, 64);
    s += __shfl_xor(s, 2, 64);
    const float tl = __shfl(tail, cc, 64);
    if (qq == 0) logits[(size_t)b * NCAND + mbase + cc] = s + tl;
}

extern "C" void kernel_launch(void* const* d_in, const int* in_sizes, int n_in,
                              void* d_out, int out_size, void* d_ws, size_t ws_size,
                              hipStream_t stream) {
    const int*   src         = (const int*)d_in[0];
    const int*   dest        = (const int*)d_in[1];
    const int*   tt          = (const int*)d_in[2];
    const int*   candidates  = (const int*)d_in[3];
    const float* offset      = (const float*)d_in[4];
    const float* emb_feat    = (const float*)d_in[5];
    const float* emb_dest    = (const float*)d_in[6];
    const float* w1          = (const float*)d_in[7];
    const float* b1          = (const float*)d_in[8];
    const float* bn_gamma    = (const float*)d_in[9];
    const float* bn_beta     = (const float*)d_in[10];
    const float* bn_mean     = (const float*)d_in[11];
    const float* bn_var      = (const float*)d_in[12];
    const float* w2          = (const float*)d_in[13];
    const float* b2          = (const float*)d_in[14];
    const float* dense_w     = (const float*)d_in[15];
    const float* dense_b     = (const float*)d_in[16];
    const float* cand_w      = (const float*)d_in[17];
    const float* cand_b      = (const float*)d_in[18];
    const float* segs_src    = (const float*)d_in[19];
    const float* segs_trg    = (const float*)d_in[20];
    const float* traffic_pop = (const float*)d_in[21];

    float* out_ws = (float*)d_ws;
    const size_t OUT_WS_BYTES = (size_t)BATCH * DM8 * 4;        //  4,194,304
    const size_t WTAB_BYTES   = (size_t)SEGN * DWC * 2;         // 50,400,000
    short* wtab = (short*)((char*)d_ws + OUT_WS_BYTES);
    const bool use_tab = ws_size >= OUT_WS_BYTES + WTAB_BYTES;
    float* logits = (float*)d_out;

    if (use_tab) {
        fused_kernel<true><<<MLP_BLOCKS + CONV_BLOCKS, 512, 0, stream>>>(
            src, dest, offset, emb_feat, emb_dest,
            w1, b1, bn_gamma, bn_beta, bn_mean, bn_var, w2, b2,
            dense_w, wtab, out_ws);
        logits_kernel_t<true><<<BATCH, 256, 0, stream>>>(
            dest, tt, candidates, dense_w, (const unsigned short*)wtab, dense_b,
            cand_w, cand_b, segs_src, segs_trg, traffic_pop, out_ws, logits);
    } else {
        fused_kernel<false><<<MLP_BLOCKS, 512, 0, stream>>>(
            src, dest, offset, emb_feat, emb_dest,
            w1, b1, bn_gamma, bn_beta, bn_mean, bn_var, w2, b2,
            dense_w, wtab, out_ws);
        logits_kernel_t<false><<<BATCH, 256, 0, stream>>>(
            dest, tt, candidates, dense_w, (const unsigned short*)wtab, dense_b,
            cand_w, cand_b, segs_src, segs_trg, traffic_pop, out_ws, logits);
    }
}